// Round 14
// baseline (50510.324 us; speedup 1.0000x reference)
//
#include <hip/hip_runtime.h>
#include <math.h>

// FISTA compressed-sensing loop, fused + 4-way split: ONE kernel, 200
// iterations, FOUR 1024-thread blocks per batch image (256 blocks = all CUs).
//
// R14 rationale: R13 (3.44 ms, 17.2 us/iter) is VALU-issue-bound at ~84% on
// the 64 ACTIVE CUs -- 192 CUs idle. Split each image across 4 blocks, each
// holding a FULL LDS mirror of y (stage bodies verbatim; only the
// thread->work mapping changes): stage-1's 27 jobs over 64 worker-waves
// (<=1 job/wave), stage-2 by m-range. Coupling through d_ws: Ap partials +
// Yg write-through/import; 2 spin-barriers/iter (monotone per-image atomic
// counter, device-scope, release-fence before arrival / acquire loads).
// Co-residency: 256 WG x 16 waves <= 512 WG capacity -> no deadlock.
// Race audit: Ap(k+1) writes gated by barrier2(k) (all blocks past
// pre-pass(k)+stage-2(k)); Yg(k+1) writes gated by barrier1(k+1), which
// each block reaches only after finishing its import(k).
//
// Phase decomposition (proven R2-R13): ih = 8*qh + ph. A (40x40 s8 SAME) =
// sum over 64 phases of 5x5 convs on the 9x9 grid. At (k=5 s8 SAME, jax
// pads (4,7)): elementwise with zero-filled Wct. y layout (phase-minor,
// LDS + Yg): y[(r*27 + wc*3 + ci)*64 + p], p = ph*8+pw.

#define ITERS 200
#define THREADS 1024
#define NWAVES 16
#define YN 15552                 // LDS: a[243] after Y
#define SMEM_FLOATS (YN + 243)   // 63,180 B
// d_ws float offsets:
#define WAOFF 0                  // 14400
#define WCTOFF 14400             // 576
#define YGOFF 14976              // 995,328 (64 images x 15552)
#define APOFF 1010304            // 46,656  (64 images x 729)
#define CNTOFF 1056960           // 64 ints (barrier counters)
                                 // total 1,057,024 floats ~= 4.23 MB

template <int CTRL>
__device__ __forceinline__ float dpp_add(float x) {
  int moved = __builtin_amdgcn_update_dpp(0, __float_as_int(x), CTRL, 0xF, 0xF, true);
  return x + __int_as_float(moved);
}
// gfx9 wave64 sum; result valid in lane 63. Proven R2-R13.
__device__ __forceinline__ float wave_sum64_to_lane63(float x) {
  x = dpp_add<0x111>(x);
  x = dpp_add<0x112>(x);
  x = dpp_add<0x114>(x);
  x = dpp_add<0x118>(x);
  x = dpp_add<0x142>(x);
  x = dpp_add<0x143>(x);
  return x;
}

// Weight reorder (R10-proven layouts) + barrier-counter zeroing.
__global__ void k0_init(const float* __restrict__ w_conv,
                        const float* __restrict__ w_ct,
                        float* __restrict__ ws) {
  const int i = blockIdx.x * 256 + threadIdx.x;
  if (i < 14400) {
    const int p = i % 64;
    const int rest = i / 64;       // (t*3+ci)*3+co
    const int co = rest % 3;
    const int rest2 = rest / 3;
    const int ci = rest2 % 3;
    const int t = rest2 / 3;       // th*5+tw
    const int tw = t % 5;
    const int th = t / 5;
    const int pw = p % 8;
    const int ph = p / 8;
    ws[WAOFF + i] = w_conv[(((8 * th + ph) * 40 + (8 * tw + pw)) * 3 + ci) * 3 + co];
  }
  if (i < 576) {
    const int ci = i % 3;
    const int r1 = i / 3;
    const int c = r1 % 3;
    const int r2 = r1 / 3;
    const int rw = r2 % 8;
    const int rh = r2 / 8;
    float v = 0.f;
    if (rh < 5 && rw < 5) v = w_ct[(((4 - rh) * 5 + (4 - rw)) * 3 + ci) * 3 + c];
    ws[WCTOFF + i] = v;
  }
  if (i < 64) ((int*)ws)[CNTOFF + i] = 0;   // barrier counters
}

__global__ __launch_bounds__(THREADS) void fista_fused(
    float* __restrict__ ws,
    const float* __restrict__ x, const float* __restrict__ lam,
    const float* __restrict__ b_conv, const float* __restrict__ b_ct,
    float* __restrict__ out) {
  __shared__ float smem[SMEM_FLOATS];
  const int tid = threadIdx.x;
  const int blk = blockIdx.x;     // 0..255
  const int n = blk >> 2;         // image
  const int b = blk & 3;          // sub-block 0..3
  const int p = tid & 63;         // lane = phase
  const int widx = tid >> 6;      // 0..15

  const float* __restrict__ WA  = ws + WAOFF;
  const float* __restrict__ WCT = ws + WCTOFF;
  float* __restrict__ Yg = ws + YGOFF + n * 15552;
  float* __restrict__ Ap = ws + APOFF + n * 729;
  int* __restrict__ cnt = (int*)ws + CNTOFF + n;

  const float lam_n = lam[n];
  const float bc_pre = (tid < 243) ? b_conv[tid % 3] : 0.f;

  const int mstart = 61 * b;
  const int mend = (b == 3) ? 243 : (mstart + 61);
  const int j2 = b + 4 * widx;    // this wave's stage-1 job (may be >= 27)
  const int ci1 = (j2 < 27) ? (j2 / 9) : 0;
  const int oh1 = (j2 < 27) ? (j2 - ci1 * 9) : 0;

  // zero local Y mirror + a (iter-0 y_tmp = 0 in all mirrors)
  for (int i = tid; i < SMEM_FLOATS; i += THREADS) smem[i] = 0.f;
  __syncthreads();

  int bargen = 0;
  float t = 1.0f;
#pragma unroll 1
  for (int iter = 0; iter < ITERS; ++iter) {
    // ===== stage 1: ci-partial conv; job (oh1,ci1); dest = Ap (global) ========
    if (j2 < 27) {
      float acc[27];               // [ow*3 + co]
#pragma unroll
      for (int k = 0; k < 27; ++k) acc[k] = 0.f;

#pragma unroll
      for (int th = 0; th < 5; ++th) {
        const int r = oh1 + th - 2;         // input row
        if (r >= 0 && r <= 8) {
          float rv[13];                     // y col (k-2), zero-padded
          rv[0] = 0.f; rv[1] = 0.f; rv[11] = 0.f; rv[12] = 0.f;
#pragma unroll
          for (int k = 2; k <= 10; ++k)
            rv[k] = smem[(r * 27 + (k - 2) * 3 + ci1) * 64 + p];

#pragma unroll
          for (int tw = 0; tw < 5; ++tw) {
            const int wb = ((th * 5 + tw) * 3 + ci1) * 3;
            const float w0 = WA[(wb + 0) * 64 + p];
            const float w1 = WA[(wb + 1) * 64 + p];
            const float w2 = WA[(wb + 2) * 64 + p];
#pragma unroll
            for (int ow = 0; ow < 9; ++ow) {
              const float y = rv[ow + tw];
              acc[ow * 3 + 0] += y * w0;
              acc[ow * 3 + 1] += y * w1;
              acc[ow * 3 + 2] += y * w2;
            }
          }
        }
      }

#pragma unroll
      for (int k = 0; k < 27; ++k) acc[k] = wave_sum64_to_lane63(acc[k]);
      if (p == 63) {
#pragma unroll
        for (int k = 0; k < 27; ++k)
          Ap[ci1 * 243 + oh1 * 27 + k] = acc[k];
      }
    }

    // ===== barrier 1 (Ap complete across the image's 4 blocks) ===============
    __threadfence();
    __syncthreads();
    ++bargen;
    if (tid == 0) {
      atomicAdd(cnt, 1);
      while (__hip_atomic_load(cnt, __ATOMIC_ACQUIRE, __HIP_MEMORY_SCOPE_AGENT)
             < 4 * bargen) {}
    }
    __syncthreads();

    // ===== pre-pass: a = sum_ci Ap + b_conv -> LDS (R13 sum order) ===========
    if (tid < 243)
      smem[YN + tid] = Ap[tid] + Ap[243 + tid] + Ap[486 + tid] + bc_pre;
    __syncthreads();

    const float tn = (1.0f + sqrtf(1.0f + 4.0f * t * t)) * 0.5f;
    const float beta = (t - 1.0f) / tn;          // beta_0 = 0
    t = tn;

    // ===== stage 2: elementwise for m in [mstart, mend) ======================
    const bool lastit = (iter == ITERS - 1);
#pragma unroll 1
    for (int m = mstart + widx; m < mend; m += NWAVES) {   // wave-uniform m
      const int cdiv = m / 3;                    // cell
      const int c = m - 3 * cdiv;
      const int cb = 3 * cdiv;

      const float a0 = smem[YN + cb + 0];
      const float a1 = smem[YN + cb + 1];
      const float a2 = smem[YN + cb + 2];
      const float r0 = x[n * 243 + cb + 0] - a0;
      const float r1 = x[n * 243 + cb + 1] - a1;
      const float r2v = x[n * 243 + cb + 2] - a2;

      const float* wp = WCT + (p * 3 + c) * 3;
      const float re = b_ct[c] + r0 * wp[0] + r1 * wp[1] + r2v * wp[2];

      const int e = m * 64 + p;
      const float yt = smem[e];
      const float wv = yt - re;
      const float yn_ = fmaxf(wv - lam_n, 0.f) - fmaxf(-wv - lam_n, 0.f);

      if (!lastit) {
        const float yl = out[n * 15552 + e];     // ylast scratch in d_out
        out[n * 15552 + e] = yn_;
        const float ytmp = yn_ + beta * (yn_ - yl);
        smem[e] = ytmp;
        Yg[e] = ytmp;                            // write-through for peers
      } else {
        const int part = p >> 3;
        const int rw = p & 7;
        const int qh = cdiv / 9;
        const int qw = cdiv - 9 * qh;
        const int ih = 8 * qh + part;
        const int iw = 8 * qw + rw;
        out[((n * 72 + ih) * 72 + iw) * 3 + c] = yn_;
      }
    }

    if (!lastit) {
      // ===== barrier 2 (Yg quarters complete) + import peers' quarters =======
      __threadfence();
      __syncthreads();
      ++bargen;
      if (tid == 0) {
        atomicAdd(cnt, 1);
        while (__hip_atomic_load(cnt, __ATOMIC_ACQUIRE, __HIP_MEMORY_SCOPE_AGENT)
               < 4 * bargen) {}
      }
      __syncthreads();
#pragma unroll 1
      for (int e = tid; e < 15552; e += THREADS) {
        const int m = e >> 6;                    // wave-uniform (64 | stride)
        if (m < mstart || m >= mend) smem[e] = Yg[e];
      }
      __syncthreads();
    }
  }
}

extern "C" void kernel_launch(void* const* d_in, const int* in_sizes, int n_in,
                              void* d_out, int out_size, void* d_ws, size_t ws_size,
                              hipStream_t stream) {
  const float* x      = (const float*)d_in[0];
  const float* lam    = (const float*)d_in[1];
  const float* w_conv = (const float*)d_in[2];
  const float* b_conv = (const float*)d_in[3];
  const float* w_ct   = (const float*)d_in[4];
  const float* b_ct   = (const float*)d_in[5];
  float* out = (float*)d_out;
  float* ws  = (float*)d_ws;  // needs ~4.23 MB

  hipLaunchKernelGGL(k0_init, dim3(57), dim3(256), 0, stream, w_conv, w_ct, ws);
  hipLaunchKernelGGL(fista_fused, dim3(256), dim3(THREADS), 0, stream,
                     ws, x, lam, b_conv, b_ct, out);
}

// Round 15
// 3675.911 us; speedup vs baseline: 13.7409x; 13.7409x over previous
//
#include <hip/hip_runtime.h>
#include <math.h>

// FISTA, phase-split 4x: 256 blocks = (64 images) x (4 phase-groups of 16),
// 576 threads (9 waves), 200 iterations in-kernel, ONE cross-block barrier
// per iteration exchanging only 243-float partial a's (double-buffered).
//
// R14 lessons baked in: (1) barrier counters padded 256 B apart (R14's 4 B
// spacing -> line contention, 98 GB/s spin traffic); (2) s_sleep backoff;
// (3) ylast/y/weights all in LDS -> fence dirty set ~1 KB (R14's 60 KB/iter
// write-through made __threadfence flush GBs to HBM); (4) one barrier, not
// two: y is block-local under the phase split, so only a-partials cross.
// Double-buffered Ap removes the WAR hazard: buffer k%2 is rewritten only
// after barrier k+1, which requires every peer finished reading it.
//
// Phase decomposition (proven R2-R13): a[cell,co] = sum_{dcell(5x5), ci, p}
// y[cell+d, ci, p] W[d,ci,p,co]; block g sums its 16 phases -> partial a.
// Stage-2 (At + soft-threshold + momentum) is elementwise per (cell,c,p),
// p-local to the block. Wave = oh; lane = (q=ci quadrant, p_local); q=3
// lanes have zero weights (their y reads duplicate q=2: same-address LDS
// broadcast, free). Straight-line body from R13 (no lambdas).

#define ITERS 200
#define THREADS 576
// d_ws float offsets
#define WGOFF 0          // 19200: [g][t*3+co][lane], q=3 lanes zeroed
#define WCTOFF 19200     // 576
#define APOFF 19776      // 2 * 64 * 4 * 243 = 124416 (double-buffered)
#define CNTOFF 144192    // 64 images x 64-int padding (256 B apart)
// LDS float offsets
#define LY 0             // y: 3888 = 243 idx3 x 16 p_local
#define LYL 3888         // y_last: 3888
#define LA 7776          // a: 243
#define LWG 8019         // weights g-slice: 4800
#define LWCT 12819       // Wct: 576
#define LXS 13395        // x image slice: 243
#define SMEMF 13638      // 54,552 B

template <int CTRL>
__device__ __forceinline__ float dpp_add(float x) {
  int moved = __builtin_amdgcn_update_dpp(0, __float_as_int(x), CTRL, 0xF, 0xF, true);
  return x + __int_as_float(moved);
}
// gfx9 wave64 sum -> lane 63. Proven R2-R13.
__device__ __forceinline__ float wave_sum64_to_lane63(float x) {
  x = dpp_add<0x111>(x);
  x = dpp_add<0x112>(x);
  x = dpp_add<0x114>(x);
  x = dpp_add<0x118>(x);
  x = dpp_add<0x142>(x);
  x = dpp_add<0x143>(x);
  return x;
}

// WG[((g*75 + t*3 + co))*64 + lane] = w_conv[8*th+ph][8*tw+pw][ci=q][co]
//   with lane=(q,pl), p = g*16+pl; q==3 -> 0 (dead quadrant).
// Wct[((rh*8+rw)*3+c)*3 + ci] = (rh<5 && rw<5) ? w_ct[4-rh][4-rw][ci][c] : 0.
__global__ void k0_init(const float* __restrict__ w_conv,
                        const float* __restrict__ w_ct,
                        float* __restrict__ ws) {
  const int i = blockIdx.x * 256 + threadIdx.x;
  if (i < 19200) {
    const int lane = i & 63;
    const int rest = i >> 6;          // g*75 + t*3 + co
    const int g = rest / 75;
    const int tc = rest - 75 * g;
    const int t = tc / 3;
    const int co = tc - 3 * t;
    const int th = t / 5;
    const int tw = t - 5 * th;
    const int q = lane >> 4;
    const int pl = lane & 15;
    float v = 0.f;
    if (q < 3) {
      const int p = g * 16 + pl;
      const int ph = p >> 3;
      const int pw = p & 7;
      v = w_conv[(((8 * th + ph) * 40 + (8 * tw + pw)) * 3 + q) * 3 + co];
    }
    ws[WGOFF + i] = v;
  }
  if (i < 576) {
    const int ci = i % 3;
    const int r1 = i / 3;
    const int c = r1 % 3;
    const int r2 = r1 / 3;
    const int rw = r2 % 8;
    const int rh = r2 / 8;
    float v = 0.f;
    if (rh < 5 && rw < 5) v = w_ct[(((4 - rh) * 5 + (4 - rw)) * 3 + ci) * 3 + c];
    ws[WCTOFF + i] = v;
  }
  if (i < 4096) ((int*)ws)[CNTOFF + i] = 0;
}

__global__ __launch_bounds__(THREADS) void fista_split(
    float* __restrict__ ws,
    const float* __restrict__ x, const float* __restrict__ lam,
    const float* __restrict__ b_conv, const float* __restrict__ b_ct,
    float* __restrict__ out) {
  __shared__ float smem[SMEMF];
  const int tid = threadIdx.x;
  const int blk = blockIdx.x;
  const int n = blk >> 2;         // image
  const int g = blk & 3;          // phase-group (p = g*16 + pl)
  const int lane = tid & 63;
  const int oh = tid >> 6;        // wave index == output row (9 waves, 9 rows)
  const int q = lane >> 4;        // ci quadrant (3 = dead)
  const int pl = lane & 15;
  const int ylane = ((q < 3) ? q : 2) * 16 + pl;  // q=3 dupes q=2: broadcast

  int* __restrict__ cnt = (int*)ws + CNTOFF + n * 64;
  const float lam_n = lam[n];
  const float bcv = b_conv[tid % 3];   // pre-pass bias (used when tid<243)
  const float bct0 = b_ct[0], bct1 = b_ct[1], bct2 = b_ct[2];

  // stage LDS: zero y/ylast/a; copy weights, Wct, x-slice
  for (int i = tid; i < LWG; i += THREADS) smem[i] = 0.f;
  for (int i = tid; i < 4800; i += THREADS) smem[LWG + i] = ws[WGOFF + g * 4800 + i];
  smem[LWCT + tid] = ws[WCTOFF + tid];
  if (tid < 243) smem[LXS + tid] = x[n * 243 + tid];
  __syncthreads();

  float t = 1.0f;
#pragma unroll 1
  for (int iter = 0; iter < ITERS; ++iter) {
    // ===== stage 1: partial a over this block's 16 phases; wave = oh ==========
    {
      float acc[27];               // [ow*3 + co]
#pragma unroll
      for (int k = 0; k < 27; ++k) acc[k] = 0.f;

#pragma unroll
      for (int th = 0; th < 5; ++th) {
        const int r = oh + th - 2;          // input row
        if (r >= 0 && r <= 8) {
          float rv[13];                     // y col (k-2), zero-padded
          rv[0] = 0.f; rv[1] = 0.f; rv[11] = 0.f; rv[12] = 0.f;
#pragma unroll
          for (int wc = 0; wc < 9; ++wc)
            rv[wc + 2] = smem[LY + r * 432 + wc * 48 + ylane];

#pragma unroll
          for (int tw = 0; tw < 5; ++tw) {
            const int tb = (th * 5 + tw) * 3;
            const float w0 = smem[LWG + (tb + 0) * 64 + lane];
            const float w1 = smem[LWG + (tb + 1) * 64 + lane];
            const float w2 = smem[LWG + (tb + 2) * 64 + lane];
#pragma unroll
            for (int ow = 0; ow < 9; ++ow) {
              const float y = rv[ow + tw];
              acc[ow * 3 + 0] += y * w0;
              acc[ow * 3 + 1] += y * w1;
              acc[ow * 3 + 2] += y * w2;
            }
          }
        }
      }

#pragma unroll
      for (int k = 0; k < 27; ++k) acc[k] = wave_sum64_to_lane63(acc[k]);
      if (lane == 63) {
        float* ap = ws + APOFF + ((((iter & 1) * 64 + n) * 4 + g) * 243) + oh * 27;
#pragma unroll
        for (int k = 0; k < 27; ++k) ap[k] = acc[k];
      }
    }

    // ===== one cross-block barrier (4 blocks of this image) ===================
    __syncthreads();                       // drains vmcnt: Ap stores complete
    if (tid == 0) {
      __threadfence();                     // L2 writeback: Ap visible device-wide
      __hip_atomic_fetch_add(cnt, 1, __ATOMIC_ACQ_REL, __HIP_MEMORY_SCOPE_AGENT);
      const int target = 4 * (iter + 1);
      while (__hip_atomic_load(cnt, __ATOMIC_ACQUIRE, __HIP_MEMORY_SCOPE_AGENT)
             < target)
        __builtin_amdgcn_s_sleep(4);
    }
    __syncthreads();

    // ===== pre-pass: a = sum_g Ap + b_conv -> LDS =============================
    if (tid < 243) {
      const float* ap = ws + APOFF + ((iter & 1) * 64 + n) * 4 * 243;
      smem[LA + tid] = ap[tid] + ap[243 + tid] + ap[486 + tid] + ap[729 + tid] + bcv;
    }
    __syncthreads();

    const float tn = (1.0f + sqrtf(1.0f + 4.0f * t * t)) * 0.5f;
    const float beta = (t - 1.0f) / tn;    // beta_0 = 0
    t = tn;

    // ===== stage 2: elementwise over this block's 3888 y elements =============
    const bool lastit = (iter == ITERS - 1);
#pragma unroll 1
    for (int e = tid; e < 3888; e += THREADS) {
      const int idx3 = e >> 4;             // cell*3 + c
      const int pl2 = e & 15;
      const int cell = idx3 / 3;
      const int c = idx3 - 3 * cell;
      const int cb = 3 * cell;

      const float a0 = smem[LA + cb + 0];
      const float a1 = smem[LA + cb + 1];
      const float a2 = smem[LA + cb + 2];
      const float r0 = smem[LXS + cb + 0] - a0;
      const float r1 = smem[LXS + cb + 1] - a1;
      const float r2v = smem[LXS + cb + 2] - a2;

      const int p = g * 16 + pl2;
      const float* wp = &smem[LWCT + (p * 3 + c) * 3];
      const float bct = (c == 0) ? bct0 : ((c == 1) ? bct1 : bct2);
      const float re = bct + r0 * wp[0] + r1 * wp[1] + r2v * wp[2];

      const float yt = smem[LY + e];
      const float wv = yt - re;
      const float yn = fmaxf(wv - lam_n, 0.f) - fmaxf(-wv - lam_n, 0.f);

      if (!lastit) {
        const float yl = smem[LYL + e];
        smem[LYL + e] = yn;
        smem[LY + e] = yn + beta * (yn - yl);
      } else {
        const int part = p >> 3;
        const int rw = p & 7;
        const int qh = cell / 9;
        const int qw = cell - 9 * qh;
        const int ih = 8 * qh + part;
        const int iw = 8 * qw + rw;
        out[((n * 72 + ih) * 72 + iw) * 3 + c] = yn;
      }
    }
    __syncthreads();
  }
}

extern "C" void kernel_launch(void* const* d_in, const int* in_sizes, int n_in,
                              void* d_out, int out_size, void* d_ws, size_t ws_size,
                              hipStream_t stream) {
  const float* x      = (const float*)d_in[0];
  const float* lam    = (const float*)d_in[1];
  const float* w_conv = (const float*)d_in[2];
  const float* b_conv = (const float*)d_in[3];
  const float* w_ct   = (const float*)d_in[4];
  const float* b_ct   = (const float*)d_in[5];
  float* out = (float*)d_out;
  float* ws  = (float*)d_ws;  // needs ~593 KB

  hipLaunchKernelGGL(k0_init, dim3(80), dim3(256), 0, stream, w_conv, w_ct, ws);
  hipLaunchKernelGGL(fista_split, dim3(256), dim3(THREADS), 0, stream,
                     ws, x, lam, b_conv, b_ct, out);
}

// Round 16
// 3139.630 us; speedup vs baseline: 16.0880x; 1.1708x over previous
//
#include <hip/hip_runtime.h>
#include <math.h>

// FISTA, phase-split 4x, XCD-colocated: 256 blocks = (4 phase-groups) x (64
// images) with n = blk & 63, g = blk >> 6, so image n's four blocks are
// {n, n+64, n+128, n+192} — all congruent mod 8 -> same XCD under the
// round-robin WG->XCD dispatch heuristic. The per-iteration Ap exchange
// (243-float partials, double-buffered) then stays in ONE XCD's L2.
//
// R15 evidence: same kernel with n=blk>>2,g=blk&3 spread each image's blocks
// across 4 XCDs -> every Ap handoff crossed the non-coherent L2 boundary:
// FETCH 84 MB + WRITE 66 MB HBM (matches 199 MB Ap reads + 50 MB writes),
// ~16 us/iter barrier+exchange latency vs ~1.5 us compute. VALUBusy 22% x
// 256 CUs == R13's total VALU work, so compute distribution is correct.
// R14 lessons retained: padded counters (256 B), s_sleep backoff, y/ylast/
// weights/x in LDS (fence dirty set ~1 KB -> no fence-driven HBM flush).
//
// Phase decomposition (proven R2-R13): a[cell,co] = sum_{d(5x5), ci, p}
// y[cell+d, ci, p] W[d,ci,p,co]; block g sums its 16 phases -> partial a.
// Stage-2 elementwise per (cell,c,p), p-local. Wave = oh (9 waves); lane =
// (q=ci quadrant, p_local); q=3 lanes carry zero weights (y reads duplicate
// q=2: same-address broadcast, free).

#define ITERS 200
#define THREADS 576
// d_ws float offsets
#define WGOFF 0          // 19200: [g][t*3+co][lane], q=3 lanes zeroed
#define WCTOFF 19200     // 576
#define APOFF 19776      // 2 * 64 * 4 * 243 = 124416 (double-buffered)
#define CNTOFF 144192    // 64 images x 64-int padding (256 B apart)
// LDS float offsets
#define LY 0             // y: 3888 = 243 idx3 x 16 p_local
#define LYL 3888         // y_last: 3888
#define LA 7776          // a: 243
#define LWG 8019         // weights g-slice: 4800
#define LWCT 12819       // Wct: 576
#define LXS 13395        // x image slice: 243
#define SMEMF 13638      // 54,552 B

template <int CTRL>
__device__ __forceinline__ float dpp_add(float x) {
  int moved = __builtin_amdgcn_update_dpp(0, __float_as_int(x), CTRL, 0xF, 0xF, true);
  return x + __int_as_float(moved);
}
// gfx9 wave64 sum -> lane 63. Proven R2-R15.
__device__ __forceinline__ float wave_sum64_to_lane63(float x) {
  x = dpp_add<0x111>(x);
  x = dpp_add<0x112>(x);
  x = dpp_add<0x114>(x);
  x = dpp_add<0x118>(x);
  x = dpp_add<0x142>(x);
  x = dpp_add<0x143>(x);
  return x;
}

// WG[((g*75 + t*3 + co))*64 + lane] = w_conv[8*th+ph][8*tw+pw][ci=q][co]
//   with lane=(q,pl), p = g*16+pl; q==3 -> 0 (dead quadrant).
// Wct[((rh*8+rw)*3+c)*3 + ci] = (rh<5 && rw<5) ? w_ct[4-rh][4-rw][ci][c] : 0.
__global__ void k0_init(const float* __restrict__ w_conv,
                        const float* __restrict__ w_ct,
                        float* __restrict__ ws) {
  const int i = blockIdx.x * 256 + threadIdx.x;
  if (i < 19200) {
    const int lane = i & 63;
    const int rest = i >> 6;          // g*75 + t*3 + co
    const int g = rest / 75;
    const int tc = rest - 75 * g;
    const int t = tc / 3;
    const int co = tc - 3 * t;
    const int th = t / 5;
    const int tw = t - 5 * th;
    const int q = lane >> 4;
    const int pl = lane & 15;
    float v = 0.f;
    if (q < 3) {
      const int p = g * 16 + pl;
      const int ph = p >> 3;
      const int pw = p & 7;
      v = w_conv[(((8 * th + ph) * 40 + (8 * tw + pw)) * 3 + q) * 3 + co];
    }
    ws[WGOFF + i] = v;
  }
  if (i < 576) {
    const int ci = i % 3;
    const int r1 = i / 3;
    const int c = r1 % 3;
    const int r2 = r1 / 3;
    const int rw = r2 % 8;
    const int rh = r2 / 8;
    float v = 0.f;
    if (rh < 5 && rw < 5) v = w_ct[(((4 - rh) * 5 + (4 - rw)) * 3 + ci) * 3 + c];
    ws[WCTOFF + i] = v;
  }
  if (i < 4096) ((int*)ws)[CNTOFF + i] = 0;
}

__global__ __launch_bounds__(THREADS) void fista_split(
    float* __restrict__ ws,
    const float* __restrict__ x, const float* __restrict__ lam,
    const float* __restrict__ b_conv, const float* __restrict__ b_ct,
    float* __restrict__ out) {
  __shared__ float smem[SMEMF];
  const int tid = threadIdx.x;
  const int blk = blockIdx.x;
  const int n = blk & 63;         // image  (XCD-colocation: blocks of image n
  const int g = blk >> 6;         //  are n, n+64, n+128, n+192 — same blk%8)
  const int lane = tid & 63;
  const int oh = tid >> 6;        // wave index == output row (9 waves, 9 rows)
  const int q = lane >> 4;        // ci quadrant (3 = dead)
  const int pl = lane & 15;
  const int ylane = ((q < 3) ? q : 2) * 16 + pl;  // q=3 dupes q=2: broadcast

  int* __restrict__ cnt = (int*)ws + CNTOFF + n * 64;
  const float lam_n = lam[n];
  const float bcv = b_conv[tid % 3];   // pre-pass bias (used when tid<243)
  const float bct0 = b_ct[0], bct1 = b_ct[1], bct2 = b_ct[2];

  // stage LDS: zero y/ylast/a; copy weights, Wct, x-slice
  for (int i = tid; i < LWG; i += THREADS) smem[i] = 0.f;
  for (int i = tid; i < 4800; i += THREADS) smem[LWG + i] = ws[WGOFF + g * 4800 + i];
  smem[LWCT + tid] = ws[WCTOFF + tid];
  if (tid < 243) smem[LXS + tid] = x[n * 243 + tid];
  __syncthreads();

  float t = 1.0f;
#pragma unroll 1
  for (int iter = 0; iter < ITERS; ++iter) {
    // ===== stage 1: partial a over this block's 16 phases; wave = oh ==========
    {
      float acc[27];               // [ow*3 + co]
#pragma unroll
      for (int k = 0; k < 27; ++k) acc[k] = 0.f;

#pragma unroll
      for (int th = 0; th < 5; ++th) {
        const int r = oh + th - 2;          // input row
        if (r >= 0 && r <= 8) {
          float rv[13];                     // y col (k-2), zero-padded
          rv[0] = 0.f; rv[1] = 0.f; rv[11] = 0.f; rv[12] = 0.f;
#pragma unroll
          for (int wc = 0; wc < 9; ++wc)
            rv[wc + 2] = smem[LY + r * 432 + wc * 48 + ylane];

#pragma unroll
          for (int tw = 0; tw < 5; ++tw) {
            const int tb = (th * 5 + tw) * 3;
            const float w0 = smem[LWG + (tb + 0) * 64 + lane];
            const float w1 = smem[LWG + (tb + 1) * 64 + lane];
            const float w2 = smem[LWG + (tb + 2) * 64 + lane];
#pragma unroll
            for (int ow = 0; ow < 9; ++ow) {
              const float y = rv[ow + tw];
              acc[ow * 3 + 0] += y * w0;
              acc[ow * 3 + 1] += y * w1;
              acc[ow * 3 + 2] += y * w2;
            }
          }
        }
      }

#pragma unroll
      for (int k = 0; k < 27; ++k) acc[k] = wave_sum64_to_lane63(acc[k]);
      if (lane == 63) {
        float* ap = ws + APOFF + ((((iter & 1) * 64 + n) * 4 + g) * 243) + oh * 27;
#pragma unroll
        for (int k = 0; k < 27; ++k) ap[k] = acc[k];
      }
    }

    // ===== one cross-block barrier (4 blocks of this image, same XCD) =========
    __syncthreads();                       // drains vmcnt: Ap stores complete
    if (tid == 0) {
      __threadfence();                     // Ap visible device-wide
      __hip_atomic_fetch_add(cnt, 1, __ATOMIC_ACQ_REL, __HIP_MEMORY_SCOPE_AGENT);
      const int target = 4 * (iter + 1);
      while (__hip_atomic_load(cnt, __ATOMIC_ACQUIRE, __HIP_MEMORY_SCOPE_AGENT)
             < target)
        __builtin_amdgcn_s_sleep(2);
    }
    __syncthreads();

    // ===== pre-pass: a = sum_g Ap + b_conv -> LDS =============================
    if (tid < 243) {
      const float* ap = ws + APOFF + ((iter & 1) * 64 + n) * 4 * 243;
      smem[LA + tid] = ap[tid] + ap[243 + tid] + ap[486 + tid] + ap[729 + tid] + bcv;
    }
    __syncthreads();

    const float tn = (1.0f + sqrtf(1.0f + 4.0f * t * t)) * 0.5f;
    const float beta = (t - 1.0f) / tn;    // beta_0 = 0
    t = tn;

    // ===== stage 2: elementwise over this block's 3888 y elements =============
    const bool lastit = (iter == ITERS - 1);
#pragma unroll 1
    for (int e = tid; e < 3888; e += THREADS) {
      const int idx3 = e >> 4;             // cell*3 + c
      const int pl2 = e & 15;
      const int cell = idx3 / 3;
      const int c = idx3 - 3 * cell;
      const int cb = 3 * cell;

      const float a0 = smem[LA + cb + 0];
      const float a1 = smem[LA + cb + 1];
      const float a2 = smem[LA + cb + 2];
      const float r0 = smem[LXS + cb + 0] - a0;
      const float r1 = smem[LXS + cb + 1] - a1;
      const float r2v = smem[LXS + cb + 2] - a2;

      const int p = g * 16 + pl2;
      const float* wp = &smem[LWCT + (p * 3 + c) * 3];
      const float bct = (c == 0) ? bct0 : ((c == 1) ? bct1 : bct2);
      const float re = bct + r0 * wp[0] + r1 * wp[1] + r2v * wp[2];

      const float yt = smem[LY + e];
      const float wv = yt - re;
      const float yn = fmaxf(wv - lam_n, 0.f) - fmaxf(-wv - lam_n, 0.f);

      if (!lastit) {
        const float yl = smem[LYL + e];
        smem[LYL + e] = yn;
        smem[LY + e] = yn + beta * (yn - yl);
      } else {
        const int part = p >> 3;
        const int rw = p & 7;
        const int qh = cell / 9;
        const int qw = cell - 9 * qh;
        const int ih = 8 * qh + part;
        const int iw = 8 * qw + rw;
        out[((n * 72 + ih) * 72 + iw) * 3 + c] = yn;
      }
    }
    __syncthreads();
  }
}

extern "C" void kernel_launch(void* const* d_in, const int* in_sizes, int n_in,
                              void* d_out, int out_size, void* d_ws, size_t ws_size,
                              hipStream_t stream) {
  const float* x      = (const float*)d_in[0];
  const float* lam    = (const float*)d_in[1];
  const float* w_conv = (const float*)d_in[2];
  const float* b_conv = (const float*)d_in[3];
  const float* w_ct   = (const float*)d_in[4];
  const float* b_ct   = (const float*)d_in[5];
  float* out = (float*)d_out;
  float* ws  = (float*)d_ws;  // needs ~593 KB

  hipLaunchKernelGGL(k0_init, dim3(80), dim3(256), 0, stream, w_conv, w_ct, ws);
  hipLaunchKernelGGL(fista_split, dim3(256), dim3(THREADS), 0, stream,
                     ws, x, lam, b_conv, b_ct, out);
}

// Round 17
// 1359.489 us; speedup vs baseline: 37.1539x; 2.3094x over previous
//
#include <hip/hip_runtime.h>
#include <math.h>

// FISTA, phase-split 4x, XCD-colocated, L3-atomic exchange: 256 blocks =
// (4 phase-groups) x (64 images), n = blk & 63, g = blk >> 6 (image's four
// blocks {n, n+64, n+128, n+192} share an XCD). ONE cross-block barrier per
// iteration; ALL cross-block data moves via relaxed agent-scope atomics,
// which execute at the chip-global memory-side L3 (Infinity Cache).
//
// R16 evidence: XCD colocation cut FETCH 84->3.3 MB, but WRITE stayed 67 MB
// and sync stayed ~13 us/iter: plain Ap stores + __threadfence forced a
// buffer_wbl2 (full L2 writeback walk) every iteration per block. Fix here:
//  - Ap stores  -> __hip_atomic_store(RELAXED, AGENT)  (no dirty L2 lines)
//  - barrier    -> __syncthreads (compiler drains vmcnt: stores ACKED at L3)
//                  then RELAXED fetch_add + RELAXED spin loads (no fence, no
//                  wbl2, no inv anywhere in the loop)
//  - pre-pass   -> relaxed atomic loads (bypass stale L1/L2; L3 serializes:
//                  stores acked < counter add issued < count observed < loads)
// WAR audit (same as R16, passed): pre-pass(k) < stage1(k+1) < barrier(k+1)
// < stage1(k+2) rewrite of buffer k&1. Deterministic g0..g3 sum order kept.
//
// Phase decomposition (proven R2-R16): a[cell,co] = sum_{d(5x5),ci,p}
// y[cell+d,ci,p] W[d,ci,p,co]; block g sums its 16 phases -> partial a.
// Stage-2 elementwise per (cell,c,p), p-local, all in LDS. Wave = oh; lane =
// (q=ci quadrant, p_local); q=3 lanes carry zero weights (y reads duplicate
// q=2: same-address broadcast, free).

#define ITERS 200
#define THREADS 576
// d_ws float offsets
#define WGOFF 0          // 19200: [g][t*3+co][lane], q=3 lanes zeroed
#define WCTOFF 19200     // 576
#define APOFF 19776      // 2 * 64 * 4 * 243 = 124416 (double-buffered)
#define CNTOFF 144192    // 64 images x 64-int padding (256 B apart)
// LDS float offsets
#define LY 0             // y: 3888 = 243 idx3 x 16 p_local
#define LYL 3888         // y_last: 3888
#define LA 7776          // a: 243
#define LWG 8019         // weights g-slice: 4800
#define LWCT 12819       // Wct: 576
#define LXS 13395        // x image slice: 243
#define SMEMF 13638      // 54,552 B

template <int CTRL>
__device__ __forceinline__ float dpp_add(float x) {
  int moved = __builtin_amdgcn_update_dpp(0, __float_as_int(x), CTRL, 0xF, 0xF, true);
  return x + __int_as_float(moved);
}
// gfx9 wave64 sum -> lane 63. Proven R2-R16.
__device__ __forceinline__ float wave_sum64_to_lane63(float x) {
  x = dpp_add<0x111>(x);
  x = dpp_add<0x112>(x);
  x = dpp_add<0x114>(x);
  x = dpp_add<0x118>(x);
  x = dpp_add<0x142>(x);
  x = dpp_add<0x143>(x);
  return x;
}

// WG[((g*75 + t*3 + co))*64 + lane] = w_conv[8*th+ph][8*tw+pw][ci=q][co]
//   with lane=(q,pl), p = g*16+pl; q==3 -> 0 (dead quadrant).
// Wct[((rh*8+rw)*3+c)*3 + ci] = (rh<5 && rw<5) ? w_ct[4-rh][4-rw][ci][c] : 0.
__global__ void k0_init(const float* __restrict__ w_conv,
                        const float* __restrict__ w_ct,
                        float* __restrict__ ws) {
  const int i = blockIdx.x * 256 + threadIdx.x;
  if (i < 19200) {
    const int lane = i & 63;
    const int rest = i >> 6;          // g*75 + t*3 + co
    const int g = rest / 75;
    const int tc = rest - 75 * g;
    const int t = tc / 3;
    const int co = tc - 3 * t;
    const int th = t / 5;
    const int tw = t - 5 * th;
    const int q = lane >> 4;
    const int pl = lane & 15;
    float v = 0.f;
    if (q < 3) {
      const int p = g * 16 + pl;
      const int ph = p >> 3;
      const int pw = p & 7;
      v = w_conv[(((8 * th + ph) * 40 + (8 * tw + pw)) * 3 + q) * 3 + co];
    }
    ws[WGOFF + i] = v;
  }
  if (i < 576) {
    const int ci = i % 3;
    const int r1 = i / 3;
    const int c = r1 % 3;
    const int r2 = r1 / 3;
    const int rw = r2 % 8;
    const int rh = r2 / 8;
    float v = 0.f;
    if (rh < 5 && rw < 5) v = w_ct[(((4 - rh) * 5 + (4 - rw)) * 3 + ci) * 3 + c];
    ws[WCTOFF + i] = v;
  }
  if (i < 4096) ((int*)ws)[CNTOFF + i] = 0;
}

__global__ __launch_bounds__(THREADS) void fista_split(
    float* __restrict__ ws,
    const float* __restrict__ x, const float* __restrict__ lam,
    const float* __restrict__ b_conv, const float* __restrict__ b_ct,
    float* __restrict__ out) {
  __shared__ float smem[SMEMF];
  const int tid = threadIdx.x;
  const int blk = blockIdx.x;
  const int n = blk & 63;         // image  (XCD-colocation: blocks of image n
  const int g = blk >> 6;         //  are n, n+64, n+128, n+192 — same blk%8)
  const int lane = tid & 63;
  const int oh = tid >> 6;        // wave index == output row (9 waves, 9 rows)
  const int q = lane >> 4;        // ci quadrant (3 = dead)
  const int pl = lane & 15;
  const int ylane = ((q < 3) ? q : 2) * 16 + pl;  // q=3 dupes q=2: broadcast

  int* __restrict__ cnt = (int*)ws + CNTOFF + n * 64;
  const float lam_n = lam[n];
  const float bcv = b_conv[tid % 3];   // pre-pass bias (used when tid<243)
  const float bct0 = b_ct[0], bct1 = b_ct[1], bct2 = b_ct[2];

  // stage LDS: zero y/ylast/a; copy weights, Wct, x-slice
  for (int i = tid; i < LWG; i += THREADS) smem[i] = 0.f;
  for (int i = tid; i < 4800; i += THREADS) smem[LWG + i] = ws[WGOFF + g * 4800 + i];
  smem[LWCT + tid] = ws[WCTOFF + tid];
  if (tid < 243) smem[LXS + tid] = x[n * 243 + tid];
  __syncthreads();

  float t = 1.0f;
#pragma unroll 1
  for (int iter = 0; iter < ITERS; ++iter) {
    // ===== stage 1: partial a over this block's 16 phases; wave = oh ==========
    {
      float acc[27];               // [ow*3 + co]
#pragma unroll
      for (int k = 0; k < 27; ++k) acc[k] = 0.f;

#pragma unroll
      for (int th = 0; th < 5; ++th) {
        const int r = oh + th - 2;          // input row
        if (r >= 0 && r <= 8) {
          float rv[13];                     // y col (k-2), zero-padded
          rv[0] = 0.f; rv[1] = 0.f; rv[11] = 0.f; rv[12] = 0.f;
#pragma unroll
          for (int wc = 0; wc < 9; ++wc)
            rv[wc + 2] = smem[LY + r * 432 + wc * 48 + ylane];

#pragma unroll
          for (int tw = 0; tw < 5; ++tw) {
            const int tb = (th * 5 + tw) * 3;
            const float w0 = smem[LWG + (tb + 0) * 64 + lane];
            const float w1 = smem[LWG + (tb + 1) * 64 + lane];
            const float w2 = smem[LWG + (tb + 2) * 64 + lane];
#pragma unroll
            for (int ow = 0; ow < 9; ++ow) {
              const float y = rv[ow + tw];
              acc[ow * 3 + 0] += y * w0;
              acc[ow * 3 + 1] += y * w1;
              acc[ow * 3 + 2] += y * w2;
            }
          }
        }
      }

#pragma unroll
      for (int k = 0; k < 27; ++k) acc[k] = wave_sum64_to_lane63(acc[k]);
      if (lane == 63) {
        float* ap = ws + APOFF + ((((iter & 1) * 64 + n) * 4 + g) * 243) + oh * 27;
#pragma unroll
        for (int k = 0; k < 27; ++k)
          __hip_atomic_store(ap + k, acc[k], __ATOMIC_RELAXED,
                             __HIP_MEMORY_SCOPE_AGENT);
      }
    }

    // ===== one cross-block barrier; all data already at L3 via atomics ========
    __syncthreads();               // compiler drains vmcnt: Ap stores acked at L3
    if (tid == 0) {
      __hip_atomic_fetch_add(cnt, 1, __ATOMIC_RELAXED, __HIP_MEMORY_SCOPE_AGENT);
      const int target = 4 * (iter + 1);
      while (__hip_atomic_load(cnt, __ATOMIC_RELAXED, __HIP_MEMORY_SCOPE_AGENT)
             < target)
        __builtin_amdgcn_s_sleep(1);
    }
    __syncthreads();

    // ===== pre-pass: a = sum_g Ap + b_conv -> LDS (atomic loads: L3-fresh) ====
    if (tid < 243) {
      const float* ap = ws + APOFF + ((iter & 1) * 64 + n) * 4 * 243;
      const float a0 = __hip_atomic_load(ap + tid, __ATOMIC_RELAXED,
                                         __HIP_MEMORY_SCOPE_AGENT);
      const float a1 = __hip_atomic_load(ap + 243 + tid, __ATOMIC_RELAXED,
                                         __HIP_MEMORY_SCOPE_AGENT);
      const float a2 = __hip_atomic_load(ap + 486 + tid, __ATOMIC_RELAXED,
                                         __HIP_MEMORY_SCOPE_AGENT);
      const float a3 = __hip_atomic_load(ap + 729 + tid, __ATOMIC_RELAXED,
                                         __HIP_MEMORY_SCOPE_AGENT);
      smem[LA + tid] = a0 + a1 + a2 + a3 + bcv;
    }
    __syncthreads();

    const float tn = (1.0f + sqrtf(1.0f + 4.0f * t * t)) * 0.5f;
    const float beta = (t - 1.0f) / tn;    // beta_0 = 0
    t = tn;

    // ===== stage 2: elementwise over this block's 3888 y elements =============
    const bool lastit = (iter == ITERS - 1);
#pragma unroll 1
    for (int e = tid; e < 3888; e += THREADS) {
      const int idx3 = e >> 4;             // cell*3 + c
      const int pl2 = e & 15;
      const int cell = idx3 / 3;
      const int c = idx3 - 3 * cell;
      const int cb = 3 * cell;

      const float a0 = smem[LA + cb + 0];
      const float a1 = smem[LA + cb + 1];
      const float a2 = smem[LA + cb + 2];
      const float r0 = smem[LXS + cb + 0] - a0;
      const float r1 = smem[LXS + cb + 1] - a1;
      const float r2v = smem[LXS + cb + 2] - a2;

      const int p = g * 16 + pl2;
      const float* wp = &smem[LWCT + (p * 3 + c) * 3];
      const float bct = (c == 0) ? bct0 : ((c == 1) ? bct1 : bct2);
      const float re = bct + r0 * wp[0] + r1 * wp[1] + r2v * wp[2];

      const float yt = smem[LY + e];
      const float wv = yt - re;
      const float yn = fmaxf(wv - lam_n, 0.f) - fmaxf(-wv - lam_n, 0.f);

      if (!lastit) {
        const float yl = smem[LYL + e];
        smem[LYL + e] = yn;
        smem[LY + e] = yn + beta * (yn - yl);
      } else {
        const int part = p >> 3;
        const int rw = p & 7;
        const int qh = cell / 9;
        const int qw = cell - 9 * qh;
        const int ih = 8 * qh + part;
        const int iw = 8 * qw + rw;
        out[((n * 72 + ih) * 72 + iw) * 3 + c] = yn;
      }
    }
    __syncthreads();
  }
}

extern "C" void kernel_launch(void* const* d_in, const int* in_sizes, int n_in,
                              void* d_out, int out_size, void* d_ws, size_t ws_size,
                              hipStream_t stream) {
  const float* x      = (const float*)d_in[0];
  const float* lam    = (const float*)d_in[1];
  const float* w_conv = (const float*)d_in[2];
  const float* b_conv = (const float*)d_in[3];
  const float* w_ct   = (const float*)d_in[4];
  const float* b_ct   = (const float*)d_in[5];
  float* out = (float*)d_out;
  float* ws  = (float*)d_ws;  // needs ~593 KB

  hipLaunchKernelGGL(k0_init, dim3(80), dim3(256), 0, stream, w_conv, w_ct, ws);
  hipLaunchKernelGGL(fista_split, dim3(256), dim3(THREADS), 0, stream,
                     ws, x, lam, b_conv, b_ct, out);
}